// Round 1
// baseline (114.570 us; speedup 1.0000x reference)
//
#include <hip/hip_runtime.h>

#define OUTS 7

__global__ __launch_bounds__(256) void roipool_kernel(
    const float* __restrict__ images, const float* __restrict__ rois,
    const int* __restrict__ roi_idx, float* __restrict__ out,
    int C, int H, int W, int R)
{
    int tid = blockIdx.x * blockDim.x + threadIdx.x;
    int total = R * C * OUTS * OUTS;
    if (tid >= total) return;

    int j  = tid % OUTS;
    int t1 = tid / OUTS;
    int i  = t1 % OUTS;
    int t2 = t1 / OUTS;
    int c  = t2 % C;
    int r  = t2 / C;

    // ROI box in pixel coords, PyTorch-adaptive bin edges (reference semantics)
    float4 rv = reinterpret_cast<const float4*>(rois)[r];
    int x1 = (int)floorf(rv.x * (float)W);
    int y1 = (int)floorf(rv.y * (float)H);
    int x2 = (int)ceilf (rv.z * (float)W);
    int y2 = (int)ceilf (rv.w * (float)H);
    int Hr = y2 - y1;
    int Wr = x2 - x1;

    int sy = y1 + (i * Hr) / OUTS;
    int ey = y1 + ((i + 1) * Hr + OUTS - 1) / OUTS;
    int sx = x1 + (j * Wr) / OUTS;
    int ex = x1 + ((j + 1) * Wr + OUTS - 1) / OUTS;

    int n = roi_idx[r];
    const float* plane = images + ((size_t)(n * C + c)) * (size_t)(H * W);

    // Empty bin -> finfo(float32).min, matching jnp.where(mask, x, neg) + max
    float m = -3.402823466e+38f;
    for (int y = sy; y < ey; ++y) {
        const float* row = plane + (size_t)y * W;
        for (int x = sx; x < ex; ++x)
            m = fmaxf(m, row[x]);
    }
    out[tid] = m;
}

extern "C" void kernel_launch(void* const* d_in, const int* in_sizes, int n_in,
                              void* d_out, int out_size, void* d_ws, size_t ws_size,
                              hipStream_t stream) {
    const float* images  = (const float*)d_in[0];
    const float* rois    = (const float*)d_in[1];
    const int*   roi_idx = (const int*)d_in[2];
    float* out = (float*)d_out;

    const int C = 256, H = 56, W = 56;
    int R = in_sizes[2];                    // 256
    int total = R * C * OUTS * OUTS;        // 3,211,264

    int block = 256;
    int grid = (total + block - 1) / block; // 12,544
    roipool_kernel<<<grid, block, 0, stream>>>(images, rois, roi_idx, out, C, H, W, R);
}

// Round 2
// 110.523 us; speedup vs baseline: 1.0366x; 1.0366x over previous
//
#include <hip/hip_runtime.h>

#define OUTS 7
#define CC 256
#define HH 56
#define WW 56

// One block per (image n, channel c) plane. Stage the 56x56 plane into LDS
// once (coalesced float4), compact the ROIs belonging to image n, then
// compute all count*49 adaptive-max bins from LDS. Each image byte is
// fetched exactly once -> compulsory HBM traffic only.
__global__ __launch_bounds__(256) void roipool_kernel(
    const float* __restrict__ images, const float* __restrict__ rois,
    const int* __restrict__ roi_idx, float* __restrict__ out, int R)
{
    __shared__ float plane[HH * WW];   // 12544 B
    __shared__ int   list[256];        // matching ROI indices (R == 256)
    __shared__ int   cnt;

    const int b = blockIdx.x;
    const int n = b / CC;
    const int c = b % CC;
    const int t = threadIdx.x;

    if (t == 0) cnt = 0;
    __syncthreads();

    // Compact ROIs whose source image is n (order irrelevant: disjoint outputs).
    for (int r = t; r < R; r += 256) {
        if (roi_idx[r] == n) {
            int p = atomicAdd(&cnt, 1);
            list[p] = r;
        }
    }

    // Stage plane -> LDS, coalesced 16B loads (plane base is 16B-aligned:
    // 56*56*4 = 12544 % 16 == 0).
    const float4* src = reinterpret_cast<const float4*>(
        images + (size_t)(n * CC + c) * (HH * WW));
    float4* dst = reinterpret_cast<float4*>(plane);
    #pragma unroll
    for (int k = 0; k < (HH * WW) / 4 / 256 + 1; ++k) {
        int idx = t + k * 256;
        if (idx < (HH * WW) / 4) dst[idx] = src[idx];
    }

    __syncthreads();

    const int count = cnt;
    const int total = count * (OUTS * OUTS);
    for (int task = t; task < total; task += 256) {
        int m   = task / (OUTS * OUTS);
        int bin = task - m * (OUTS * OUTS);
        int r   = list[m];
        int i   = bin / OUTS;
        int j   = bin - i * OUTS;

        float4 rv = reinterpret_cast<const float4*>(rois)[r];
        int x1 = (int)floorf(rv.x * (float)WW);
        int y1 = (int)floorf(rv.y * (float)HH);
        int x2 = (int)ceilf (rv.z * (float)WW);
        int y2 = (int)ceilf (rv.w * (float)HH);
        int Hr = y2 - y1;
        int Wr = x2 - x1;

        int sy = y1 + (i * Hr) / OUTS;
        int ey = y1 + ((i + 1) * Hr + OUTS - 1) / OUTS;
        int sx = x1 + (j * Wr) / OUTS;
        int ex = x1 + ((j + 1) * Wr + OUTS - 1) / OUTS;

        float mx = -3.402823466e+38f;   // finfo(float32).min (empty-bin value)
        for (int y = sy; y < ey; ++y) {
            const float* row = plane + y * WW;
            for (int x = sx; x < ex; ++x)
                mx = fmaxf(mx, row[x]);
        }
        out[((size_t)r * CC + c) * (OUTS * OUTS) + bin] = mx;
    }
}

extern "C" void kernel_launch(void* const* d_in, const int* in_sizes, int n_in,
                              void* d_out, int out_size, void* d_ws, size_t ws_size,
                              hipStream_t stream) {
    const float* images  = (const float*)d_in[0];
    const float* rois    = (const float*)d_in[1];
    const int*   roi_idx = (const int*)d_in[2];
    float* out = (float*)d_out;

    int R = in_sizes[2];                         // 256
    int N = in_sizes[0] / (CC * HH * WW);        // 8

    int grid = N * CC;                           // 2048 blocks, one per plane
    roipool_kernel<<<grid, 256, 0, stream>>>(images, rois, roi_idx, out, R);
}

// Round 3
// 110.430 us; speedup vs baseline: 1.0375x; 1.0008x over previous
//
#include <hip/hip_runtime.h>

#define OUTS 7
#define CC 256
#define HH 56
#define WW 56

// One block per (image n, channel c) plane; plane staged to LDS once.
// Work mapping: one ROI per wave-pass, lane = bin index (lanes 0..48).
// Within a single ROI the 49 bins have near-identical rectangle sizes
// (differ by <=1 row/col), so the inner scan loops are wave-uniform ->
// no exec-mask divergence waste, no per-task div/mod.
__global__ __launch_bounds__(256) void roipool_kernel(
    const float* __restrict__ images, const float* __restrict__ rois,
    const int* __restrict__ roi_idx, float* __restrict__ out, int R)
{
    __shared__ float plane[HH * WW];   // 12544 B
    __shared__ int   list[256];        // ROI indices for this image (R == 256)
    __shared__ int   cnt;

    const int b = blockIdx.x;
    const int n = b / CC;
    const int c = b % CC;
    const int t = threadIdx.x;

    if (t == 0) cnt = 0;
    __syncthreads();

    // Compact ROIs whose source image is n (order irrelevant: disjoint outputs).
    for (int r = t; r < R; r += 256) {
        if (roi_idx[r] == n) {
            int p = atomicAdd(&cnt, 1);
            list[p] = r;
        }
    }

    // Stage plane -> LDS, coalesced 16B loads (784 float4 / 256 threads).
    const float4* src = reinterpret_cast<const float4*>(
        images + (size_t)(n * CC + c) * (HH * WW));
    float4* dst = reinterpret_cast<float4*>(plane);
    #pragma unroll
    for (int k = 0; k < 4; ++k) {
        int idx = t + k * 256;
        if (idx < (HH * WW) / 4) dst[idx] = src[idx];
    }

    __syncthreads();

    const int count = cnt;
    const int wv   = t >> 6;        // wave id 0..3
    const int lane = t & 63;
    const int i = lane / OUTS;      // bin row (lane < 49)
    const int j = lane - i * OUTS;  // bin col

    for (int m = wv; m < count; m += 4) {
        int r = list[m];
        if (lane >= OUTS * OUTS) continue;

        // Wave-uniform ROI box (broadcast load), per-lane bin edges.
        float4 rv = reinterpret_cast<const float4*>(rois)[r];
        int x1 = (int)floorf(rv.x * (float)WW);
        int y1 = (int)floorf(rv.y * (float)HH);
        int x2 = (int)ceilf (rv.z * (float)WW);
        int y2 = (int)ceilf (rv.w * (float)HH);
        int Hr = y2 - y1;
        int Wr = x2 - x1;

        int sy = y1 + (i * Hr) / OUTS;
        int ey = y1 + ((i + 1) * Hr + OUTS - 1) / OUTS;
        int sx = x1 + (j * Wr) / OUTS;
        int ex = x1 + ((j + 1) * Wr + OUTS - 1) / OUTS;

        float mx = -3.402823466e+38f;   // finfo(float32).min (empty-bin value)
        for (int y = sy; y < ey; ++y) {
            const float* row = plane + y * WW;
            for (int x = sx; x < ex; ++x)
                mx = fmaxf(mx, row[x]);
        }
        // 49 consecutive floats per (r,c): coalesced enough (2 cachelines).
        out[((size_t)r * CC + c) * (OUTS * OUTS) + lane] = mx;
    }
}

extern "C" void kernel_launch(void* const* d_in, const int* in_sizes, int n_in,
                              void* d_out, int out_size, void* d_ws, size_t ws_size,
                              hipStream_t stream) {
    const float* images  = (const float*)d_in[0];
    const float* rois    = (const float*)d_in[1];
    const int*   roi_idx = (const int*)d_in[2];
    float* out = (float*)d_out;

    int R = in_sizes[2];                         // 256
    int N = in_sizes[0] / (CC * HH * WW);        // 8

    int grid = N * CC;                           // 2048 blocks, one per plane
    roipool_kernel<<<grid, 256, 0, stream>>>(images, rois, roi_idx, out, R);
}